// Round 17
// baseline (150.877 us; speedup 1.0000x reference)
//
#include <hip/hip_runtime.h>

#define Bb 8
#define Nn 20000
#define Cc 128
#define Kk 64
#define Ee 320000

#define WAVES_PER_BLOCK 4
#define NSEG 256        // segments per batch (pooled: 512 blocks * 4 waves / 8 batches)
#define SEGCAP 1280     // ceil(5000/256)=20 groups * 64 edges

typedef __attribute__((ext_vector_type(8))) short bf16x8;
typedef __attribute__((ext_vector_type(16))) float f32x16;

__device__ __forceinline__ unsigned short f2bf(float f) {
    unsigned int u = __float_as_uint(f);
    u += 0x7FFFu + ((u >> 16) & 1u);          // round-to-nearest-even
    return (unsigned short)(u >> 16);
}
__device__ __forceinline__ float bf2f(unsigned int bits16) {
    return __uint_as_float(bits16 << 16);
}

// ---------------------------------------------------------------------------
// Kernel 0: one-time W1/W2 -> bf16 fragment tables in ws (proven R15/R16)
// ---------------------------------------------------------------------------
__global__ __launch_bounds__(256) void k_prep(
    const float* __restrict__ W1, const float* __restrict__ W2,
    unsigned short* __restrict__ Wf)
{
    const int tid = threadIdx.x;
    for (int idx = tid; idx < 8192; idx += 256) {
        const int j  = idx & 7;
        const int ln = (idx >> 3) & 63;
        const int t  = idx >> 9;
        const int kh = t & 1;
        const int cs = t >> 1;
        Wf[idx] = f2bf(W1[(cs * 16 + (ln >> 5) * 8 + j) * Kk + kh * 32 + (ln & 31)]);
    }
    for (int idx = tid; idx < 4096; idx += 256) {
        const int j  = idx & 7;
        const int ln = (idx >> 3) & 63;
        const int t  = idx >> 9;
        const int lh = t & 1;
        const int ks = t >> 1;
        Wf[8192 + idx] = f2bf(W2[(ks * 16 + (ln >> 5) * 8 + j) * Kk + lh * 32 + (ln & 31)]);
    }
}

// ---------------------------------------------------------------------------
// Kernel 0b: per-batch mask bitmaps -> ws + pmask (proven R16)
// ---------------------------------------------------------------------------
__global__ __launch_bounds__(256) void k_bitmap(
    const int* __restrict__ mask, unsigned int* __restrict__ bmg,
    float* __restrict__ pmask)
{
    __shared__ int s_any;
    const int tid  = threadIdx.x;
    const int lane = tid & 63;
    const int wid  = tid >> 6;
    const int b    = blockIdx.x & 7;
    const int part = blockIdx.x >> 3;               // 0..7
    if (tid == 0) s_any = 0;
    __syncthreads();

    const int* mb = mask + (size_t)b * Nn;
    int any = 0;
    for (int g = part * 4 + wid; g < 313; g += 32) {    // 313*64 >= 20000
        const int i = g * 64 + lane;
        const bool mv = (i < Nn) ? (mb[i] > 0) : false;
        const unsigned long long mk = __ballot(mv);
        if (lane == 0) {
            bmg[b * 626 + 2 * g]     = (unsigned int)mk;
            bmg[b * 626 + 2 * g + 1] = (unsigned int)(mk >> 32);
        }
        any |= (mk != 0ull) ? 1 : 0;
    }
    if (any) atomicOr(&s_any, 1);
    __syncthreads();
    if (s_any && tid < Kk) pmask[(size_t)b * Kk + tid] = 1.f;
}

// ---------------------------------------------------------------------------
// Kernel 1 (v4): S -> bf16 pair-packed Sh (proven R15: W frags from global)
// ---------------------------------------------------------------------------
__global__ __launch_bounds__(256) void k_compute_S(
    const float* __restrict__ x, const int* __restrict__ mask,
    const unsigned short* __restrict__ Wf,
    const float* __restrict__ b1, const float* __restrict__ b2,
    unsigned int* __restrict__ Sh)
{
    __shared__ float b1s[Kk];
    __shared__ float b2s[Kk];

    const int tid = threadIdx.x;
    if (tid < Kk) { b1s[tid] = b1[tid]; b2s[tid] = b2[tid]; }
    __syncthreads();

    const int lane = tid & 63;
    const int wid  = tid >> 6;
    const int hsel = lane >> 5;
    const int m32  = lane & 31;

    const int wc = blockIdx.x * WAVES_PER_BLOCK + wid;  // 0..4999 (grid=1250)
    const int chunksPerBatch = Nn / 32;                 // 625
    const int b  = wc / chunksPerBatch;
    const int n0 = (wc % chunksPerBatch) * 32;
    const int nd = n0 + m32;

    const unsigned short* W1A = Wf;
    const unsigned short* W2A = Wf + 8192;

    const float* xrow = x + ((size_t)b * Nn + nd) * Cc;
    f32x16 accA = 0.f, accB = 0.f;
    #pragma unroll
    for (int cs = 0; cs < 8; ++cs) {
        const float4 f0 = *(const float4*)&xrow[cs * 16 + hsel * 8];
        const float4 f1 = *(const float4*)&xrow[cs * 16 + hsel * 8 + 4];
        bf16x8 xa;
        xa[0] = (short)f2bf(f0.x); xa[1] = (short)f2bf(f0.y);
        xa[2] = (short)f2bf(f0.z); xa[3] = (short)f2bf(f0.w);
        xa[4] = (short)f2bf(f1.x); xa[5] = (short)f2bf(f1.y);
        xa[6] = (short)f2bf(f1.z); xa[7] = (short)f2bf(f1.w);
        const bf16x8 w1h0 = *(const bf16x8*)&W1A[((cs * 2 + 0) * 64 + lane) * 8];
        const bf16x8 w1h1 = *(const bf16x8*)&W1A[((cs * 2 + 1) * 64 + lane) * 8];
        accA = __builtin_amdgcn_mfma_f32_32x32x16_bf16(w1h0, xa, accA, 0, 0, 0);
        accB = __builtin_amdgcn_mfma_f32_32x32x16_bf16(w1h1, xa, accB, 0, 0, 0);
    }

    f32x16 accS0 = 0.f, accS1 = 0.f;

#define EXTRACT_GEMM2(KS, ACC)                                                 \
    {                                                                          \
        bf16x8 hf;                                                             \
        _Pragma("unroll")                                                      \
        for (int jj = 0; jj < 4; ++jj) {                                       \
            const int c0 = jj + 8 * ((KS) & 1);                                \
            const float own  = hsel ? (ACC)[c0 + 4] : (ACC)[c0];               \
            const float send = hsel ? (ACC)[c0]     : (ACC)[c0 + 4];           \
            const float sw   = __shfl_xor(send, 32);                           \
            const float vlo  = hsel ? sw  : own;                               \
            const float vhi  = hsel ? own : sw;                                \
            const int klo = (KS) * 16 + 8 * hsel + jj;                         \
            hf[jj]     = (short)f2bf(fmaxf(vlo + b1s[klo], 0.f));              \
            hf[jj + 4] = (short)f2bf(fmaxf(vhi + b1s[klo + 4], 0.f));          \
        }                                                                      \
        const bf16x8 w2l0 = *(const bf16x8*)&W2A[(((KS) * 2 + 0) * 64 + lane) * 8]; \
        const bf16x8 w2l1 = *(const bf16x8*)&W2A[(((KS) * 2 + 1) * 64 + lane) * 8]; \
        accS0 = __builtin_amdgcn_mfma_f32_32x32x16_bf16(w2l0, hf, accS0, 0, 0, 0); \
        accS1 = __builtin_amdgcn_mfma_f32_32x32x16_bf16(w2l1, hf, accS1, 0, 0, 0); \
    }

    EXTRACT_GEMM2(0, accA)
    EXTRACT_GEMM2(1, accA)
    EXTRACT_GEMM2(2, accB)
    EXTRACT_GEMM2(3, accB)
#undef EXTRACT_GEMM2

    float z0[16], z1[16];
    float mm = -1e30f;
    #pragma unroll
    for (int r = 0; r < 16; ++r) {
        const int l = (r & 3) + 8 * (r >> 2) + 4 * hsel;
        z0[r] = accS0[r] + b2s[l];
        z1[r] = accS1[r] + b2s[l + 32];
        mm = fmaxf(mm, fmaxf(z0[r], z1[r]));
    }
    mm = fmaxf(mm, __shfl_xor(mm, 32));
    float ssum = 0.f;
    #pragma unroll
    for (int r = 0; r < 16; ++r) {
        z0[r] = __expf(z0[r] - mm);
        z1[r] = __expf(z1[r] - mm);
        ssum += z0[r] + z1[r];
    }
    ssum += __shfl_xor(ssum, 32);
    const int   mv = mask[(size_t)b * Nn + nd];
    const float rs = (mv > 0) ? (1.f / ssum) : 0.f;

    unsigned int* ShRow = Sh + ((size_t)b * Nn + nd) * 32;
    #pragma unroll
    for (int g = 0; g < 4; ++g) {
        uint4 pk;
        pk.x = (unsigned int)f2bf(z0[4*g+0]*rs) | ((unsigned int)f2bf(z1[4*g+0]*rs) << 16);
        pk.y = (unsigned int)f2bf(z0[4*g+1]*rs) | ((unsigned int)f2bf(z1[4*g+1]*rs) << 16);
        pk.z = (unsigned int)f2bf(z0[4*g+2]*rs) | ((unsigned int)f2bf(z1[4*g+2]*rs) << 16);
        pk.w = (unsigned int)f2bf(z0[4*g+3]*rs) | ((unsigned int)f2bf(z1[4*g+3]*rs) << 16);
        *(uint4*)&ShRow[8 * g + 4 * hsel] = pk;
    }
}

// ---------------------------------------------------------------------------
// Kernel 3a (v5): compact valid edges into dense (u|v<<15, w) triplets.
// Bitmap from ws; 8-group ILP batches. NSEG=256 (512 blocks). Pads to x32.
// ---------------------------------------------------------------------------
__global__ __launch_bounds__(256) void k_compact(
    const int* __restrict__ ei, const float* __restrict__ ew,
    const unsigned int* __restrict__ bmg,
    int* __restrict__ uvp, float* __restrict__ eww, int* __restrict__ cnt)
{
    __shared__ unsigned int bm[626];                // 2.5 KB
    const int tid  = threadIdx.x;
    const int lane = tid & 63;
    const int wid  = tid >> 6;
    const int b    = blockIdx.x & 7;
    const int seg  = (blockIdx.x >> 3) * 4 + wid;   // 0..NSEG-1
    const int groupsPerBatch = Ee / 64;             // 5000
    const size_t eib = (size_t)b * 2 * Ee;
    const float* ewb = ew + (size_t)b * Ee;
    int*   uvs  = uvp + ((size_t)b * NSEG + seg) * SEGCAP;
    float* ewws = eww + ((size_t)b * NSEG + seg) * SEGCAP;

    for (int i = tid; i < 626; i += 256) bm[i] = bmg[b * 626 + i];
    __syncthreads();

    int run = 0;
    for (int g = seg; g < groupsPerBatch; g += 8 * NSEG) {
        int u8[8], v8[8]; float w8[8]; int has[8];
        #pragma unroll
        for (int t = 0; t < 8; ++t) {
            const int gg = g + t * NSEG;
            has[t] = (gg < groupsPerBatch);
            const int e0 = (has[t] ? gg : g) * 64;
            u8[t] = ei[eib + e0 + lane];
            v8[t] = ei[eib + Ee + e0 + lane];
            w8[t] = ewb[e0 + lane];
        }
        #pragma unroll
        for (int t = 0; t < 8; ++t) {
            if (!has[t]) continue;                  // wave-uniform
            const unsigned int uu = (unsigned int)u8[t];
            const unsigned int vv = (unsigned int)v8[t];
            const bool valid = ((bm[uu >> 5] >> (uu & 31)) & 1u) &&
                               ((bm[vv >> 5] >> (vv & 31)) & 1u);
            const unsigned long long mk = __ballot(valid);
            const int myoff = __popcll(mk & ((1ull << lane) - 1ull));
            if (valid) {
                uvs[run + myoff]  = u8[t] | (v8[t] << 15);
                ewws[run + myoff] = w8[t];
            }
            run += (int)__popcll(mk);
        }
    }
    const int ncp = (run + 31) & ~31;
    if (lane < ncp - run) { uvs[run + lane] = 0; ewws[run + lane] = 0.f; }
    if (lane == 0) cnt[b * NSEG + seg] = ncp;
}

// ---------------------------------------------------------------------------
// Kernel 3b (v9): pooled — 2-deep static pipeline (R12-proven) at 2 blocks/CU
// (NSEG 256 / 512 blocks) so a second wave per SIMD covers residual stalls.
// ---------------------------------------------------------------------------
template<bool USE_PT>
__global__ __launch_bounds__(256, 1) void k_pooled_edges(
    const unsigned int* __restrict__ Sh, const int* __restrict__ uvp,
    const float* __restrict__ eww, const int* __restrict__ cnt,
    float* __restrict__ out)  // pt or pooled
{
    __shared__ float tile[Kk * Kk];                 // 16 KB
    const int tid  = threadIdx.x;
    const int lane = tid & 63;
    const int wid  = tid >> 6;
    const int hsel = lane >> 5;
    const int m32  = lane & 31;

    for (int i = tid; i < Kk * Kk; i += 256) tile[i] = 0.f;
    __syncthreads();

    const int b   = blockIdx.x & 7;                 // XCD-pinned batch
    const int seg = (blockIdx.x >> 3) * 4 + wid;    // 0..NSEG-1
    const unsigned int* Shb = Sh + (size_t)b * Nn * 32;
    const int*   uvs  = uvp + ((size_t)b * NSEG + seg) * SEGCAP;
    const float* ewws = eww + ((size_t)b * NSEG + seg) * SEGCAP;
    const int nc = cnt[b * NSEG + seg];             // multiple of 32

    f32x16 acc00 = 0.f, acc01 = 0.f, acc10 = 0.f, acc11 = 0.f;

#define LOADUV(UV, WW, BASE)                                        \
    _Pragma("unroll")                                               \
    for (int j = 0; j < 8; ++j) {                                   \
        int sidx = (BASE) + hsel * 8 + j;                           \
        sidx = (sidx < nc) ? sidx : (nc - 1);                       \
        (UV)[j] = uvs[sidx];                                        \
        (WW)[j] = ewws[sidx];                                       \
    }

#define GATHER(GV, GU, UV)                                          \
    _Pragma("unroll")                                               \
    for (int j = 0; j < 8; ++j) {                                   \
        const int uu = (UV)[j] & 32767;                             \
        const int vv = ((UV)[j] >> 15) & 32767;                     \
        (GV)[j] = Shb[(size_t)vv * 32 + m32];                       \
        (GU)[j] = Shb[(size_t)uu * 32 + m32];                       \
    }

#define CONSUME(GV, GU, WW)                                         \
    {                                                               \
        bf16x8 a0, a1, b0, b1;                                      \
        _Pragma("unroll")                                           \
        for (int j = 0; j < 8; ++j) {                               \
            a0[j] = (short)f2bf((WW)[j] * bf2f((GV)[j] & 0xffffu)); \
            a1[j] = (short)f2bf((WW)[j] * bf2f((GV)[j] >> 16));     \
            b0[j] = (short)((GU)[j] & 0xffffu);                     \
            b1[j] = (short)((GU)[j] >> 16);                         \
        }                                                           \
        acc00 = __builtin_amdgcn_mfma_f32_32x32x16_bf16(a0, b0, acc00, 0, 0, 0); \
        acc01 = __builtin_amdgcn_mfma_f32_32x32x16_bf16(a0, b1, acc01, 0, 0, 0); \
        acc10 = __builtin_amdgcn_mfma_f32_32x32x16_bf16(a1, b0, acc10, 0, 0, 0); \
        acc11 = __builtin_amdgcn_mfma_f32_32x32x16_bf16(a1, b1, acc11, 0, 0, 0); \
    }

    if (nc > 0) {
        int uvA[8], uvB[8];
        float wwA[8], wwB[8];
        unsigned int gvA[8], guA[8], gvB[8], guB[8];

        LOADUV(uvA, wwA, 0)
        GATHER(gvA, guA, uvA)
        LOADUV(uvB, wwB, 16)

        for (int c0 = 0; c0 < nc; c0 += 32) {
            GATHER(gvB, guB, uvB)
            int uvA2[8], uvB2[8]; float wwA2[8], wwB2[8];
            LOADUV(uvA2, wwA2, c0 + 32)
            LOADUV(uvB2, wwB2, c0 + 48)
            CONSUME(gvA, guA, wwA)
            GATHER(gvA, guA, uvA2)
            CONSUME(gvB, guB, wwB)
            #pragma unroll
            for (int j = 0; j < 8; ++j) {
                uvB[j] = uvB2[j]; wwB[j] = wwB2[j]; wwA[j] = wwA2[j];
            }
        }
    }
#undef LOADUV
#undef GATHER
#undef CONSUME

    const int rbase = 4 * (lane >> 5);
    const int col   = lane & 31;
    #pragma unroll
    for (int r = 0; r < 16; ++r) {
        const int row = (r & 3) + 8 * (r >> 2) + rbase;
        atomicAdd(&tile[row * Kk + col],              acc00[r]);
        atomicAdd(&tile[row * Kk + 32 + col],         acc01[r]);
        atomicAdd(&tile[(32 + row) * Kk + col],       acc10[r]);
        atomicAdd(&tile[(32 + row) * Kk + 32 + col],  acc11[r]);
    }
    __syncthreads();

    if (USE_PT) {
        float* pt = out + (size_t)blockIdx.x * (Kk * Kk);
        for (int i = tid; i < Kk * Kk; i += 256) pt[i] = tile[i];
    } else {
        float* pb = out + (size_t)b * Kk * Kk;
        for (int i = tid; i < Kk * Kk; i += 256) atomicAdd(&pb[i], tile[i]);
    }
}

// ---------------------------------------------------------------------------
// Kernel 3c: sum 64 partial tiles per batch; coalesced, 64 blocks.
// ---------------------------------------------------------------------------
__global__ __launch_bounds__(256) void k_reduce_pooled(
    const float* __restrict__ pt, float* __restrict__ pooled)
{
    const int b    = blockIdx.x & 7;
    const int part = blockIdx.x >> 3;               // 0..7
    const int tid  = threadIdx.x;
    #pragma unroll
    for (int i2 = 0; i2 < 2; ++i2) {
        const int i = part * 512 + i2 * 256 + tid;
        float s = 0.f;
        #pragma unroll 8
        for (int slot = 0; slot < 64; ++slot)
            s += pt[(size_t)(slot * 8 + b) * (Kk * Kk) + i];
        pooled[(size_t)b * Kk * Kk + i] = s;
    }
}

// ---------------------------------------------------------------------------
// Kernel 4: pfeat from packed Sh (unchanged from R10-R16)
// ---------------------------------------------------------------------------
__global__ __launch_bounds__(256) void k_pfeat(
    const float* __restrict__ x, const unsigned int* __restrict__ Sh,
    float* __restrict__ pfeat)
{
    const int tid  = threadIdx.x;
    const int lane = tid & 63;
    const int wid  = tid >> 6;
    const int b    = blockIdx.x & 7;
    const int slot = blockIdx.x >> 3;
    const int bpb  = gridDim.x >> 3;

    const float* xb = x + (size_t)b * Nn * Cc;
    const unsigned int* Shb = Sh + (size_t)b * Nn * 32;

    const int nodeoff = (lane >> 5) * 8;
    const int kc      = lane & 31;
    const int c       = wid * 32 + kc;

    f32x16 acc0 = 0.f, acc1 = 0.f;

    const int chunks = Nn / 16;
    for (int ch = slot; ch < chunks; ch += bpb) {
        const int nb = ch * 16 + nodeoff;
        unsigned int g[8]; float bff[8];
        #pragma unroll
        for (int j = 0; j < 8; ++j) {
            const size_t n = (size_t)(nb + j);
            g[j]   = Shb[n * 32 + kc];
            bff[j] = xb[n * Cc + c];
        }
        bf16x8 a0, a1, bbf;
        #pragma unroll
        for (int j = 0; j < 8; ++j) {
            a0[j]  = (short)(g[j] & 0xffffu);
            a1[j]  = (short)(g[j] >> 16);
            bbf[j] = (short)f2bf(bff[j]);
        }
        acc0 = __builtin_amdgcn_mfma_f32_32x32x16_bf16(a0, bbf, acc0, 0, 0, 0);
        acc1 = __builtin_amdgcn_mfma_f32_32x32x16_bf16(a1, bbf, acc1, 0, 0, 0);
    }

    float* pf = pfeat + (size_t)b * Kk * Cc;
    const int colc  = wid * 32 + (lane & 31);
    const int rbase = 4 * (lane >> 5);
    #pragma unroll
    for (int r = 0; r < 16; ++r) {
        const int row = (r & 3) + 8 * (r >> 2) + rbase;
        atomicAdd(&pf[row * Cc + colc],        acc0[r]);
        atomicAdd(&pf[(32 + row) * Cc + colc], acc1[r]);
    }
}

// ---------------------------------------------------------------------------
extern "C" void kernel_launch(void* const* d_in, const int* in_sizes, int n_in,
                              void* d_out, int out_size, void* d_ws, size_t ws_size,
                              hipStream_t stream)
{
    const float* x    = (const float*)d_in[0];
    const int*   ei   = (const int*)d_in[1];     // int64 ref -> int32 on device
    const float* ew   = (const float*)d_in[2];
    const int*   mask = (const int*)d_in[3];
    const float* W1   = (const float*)d_in[4];
    const float* b1   = (const float*)d_in[5];
    const float* W2   = (const float*)d_in[6];
    const float* b2   = (const float*)d_in[7];

    float* out    = (float*)d_out;
    float* pfeat  = out;
    float* pooled = out + (size_t)Bb * Kk * Cc;
    float* pmask  = out + (size_t)Bb * Kk * Cc + (size_t)Bb * Kk * Kk;

    // workspace layout (essentials first, pt last)
    unsigned int* Sh = (unsigned int*)d_ws;                     // 20.48 MB
    int*   uvp  = (int*)(Sh + (size_t)Bb * Nn * 32);            // 10.49 MB
    float* eww  = (float*)(uvp + (size_t)Bb * NSEG * SEGCAP);   // 10.49 MB
    int*   cnt  = (int*)(eww + (size_t)Bb * NSEG * SEGCAP);     // 8 KB
    unsigned int* bmg = (unsigned int*)(cnt + Bb * NSEG);       // 20 KB
    unsigned short* Wf = (unsigned short*)(bmg + Bb * 626);     // 24.5 KB
    float* pt   = (float*)(Wf + 12288);                         // 8.39 MB
    const size_t needed = (size_t)((char*)(pt + (size_t)512 * Kk * Kk) - (char*)d_ws);
    const bool use_pt = ws_size >= needed;

    hipMemsetAsync(d_out, 0, sizeof(float) * (size_t)out_size, stream);

    k_prep<<<1, 256, 0, stream>>>(W1, W2, Wf);
    k_compute_S<<<1250, 256, 0, stream>>>(x, mask, Wf, b1, b2, Sh);
    k_bitmap<<<64, 256, 0, stream>>>(mask, bmg, pmask);
    k_compact<<<512, 256, 0, stream>>>(ei, ew, bmg, uvp, eww, cnt);
    if (use_pt) {
        k_pooled_edges<true><<<512, 256, 0, stream>>>(Sh, uvp, eww, cnt, pt);
        k_reduce_pooled<<<64, 256, 0, stream>>>(pt, pooled);
    } else {
        k_pooled_edges<false><<<512, 256, 0, stream>>>(Sh, uvp, eww, cnt, pooled);
    }
    k_pfeat<<<512, 256, 0, stream>>>(x, Sh, pfeat);
}

// Round 18
// 106.870 us; speedup vs baseline: 1.4118x; 1.4118x over previous
//
#include <hip/hip_runtime.h>

#define Bb 8
#define Nn 20000
#define Cc 128
#define Kk 64
#define Ee 320000

#define WAVES_PER_BLOCK 4
#define NSEG 128        // segments per batch (pooled: 256 blocks * 4 waves / 8 batches)
#define SEGCAP 2560     // ceil(5000/128)=40 groups * 64 edges

#define CS_BLOCKS 1250
#define CP_BLOCKS 256
#define PL_BLOCKS 256
#define PF_BLOCKS 512

typedef __attribute__((ext_vector_type(8))) short bf16x8;
typedef __attribute__((ext_vector_type(16))) float f32x16;

__device__ __forceinline__ unsigned short f2bf(float f) {
    unsigned int u = __float_as_uint(f);
    u += 0x7FFFu + ((u >> 16) & 1u);          // round-to-nearest-even
    return (unsigned short)(u >> 16);
}
__device__ __forceinline__ float bf2f(unsigned int bits16) {
    return __uint_as_float(bits16 << 16);
}

// ---------------------------------------------------------------------------
// Fused init: block 0 = W-fragment prep; blocks 1..64 = mask bitmaps + pmask
// ---------------------------------------------------------------------------
__global__ __launch_bounds__(256) void k_init(
    const float* __restrict__ W1, const float* __restrict__ W2,
    const int* __restrict__ mask,
    unsigned short* __restrict__ Wf, unsigned int* __restrict__ bmg,
    float* __restrict__ pmask)
{
    __shared__ int s_any;
    const int tid = threadIdx.x;

    if (blockIdx.x == 0) {
        for (int idx = tid; idx < 8192; idx += 256) {
            const int j  = idx & 7;
            const int ln = (idx >> 3) & 63;
            const int t  = idx >> 9;
            const int kh = t & 1;
            const int cs = t >> 1;
            Wf[idx] = f2bf(W1[(cs * 16 + (ln >> 5) * 8 + j) * Kk + kh * 32 + (ln & 31)]);
        }
        for (int idx = tid; idx < 4096; idx += 256) {
            const int j  = idx & 7;
            const int ln = (idx >> 3) & 63;
            const int t  = idx >> 9;
            const int lh = t & 1;
            const int ks = t >> 1;
            Wf[8192 + idx] = f2bf(W2[(ks * 16 + (ln >> 5) * 8 + j) * Kk + lh * 32 + (ln & 31)]);
        }
        return;
    }

    // bitmap part (proven R16)
    const int bid  = blockIdx.x - 1;                // 0..63
    const int lane = tid & 63;
    const int wid  = tid >> 6;
    const int b    = bid & 7;
    const int part = bid >> 3;                      // 0..7
    if (tid == 0) s_any = 0;
    __syncthreads();

    const int* mb = mask + (size_t)b * Nn;
    int any = 0;
    for (int g = part * 4 + wid; g < 313; g += 32) {    // 313*64 >= 20000
        const int i = g * 64 + lane;
        const bool mv = (i < Nn) ? (mb[i] > 0) : false;
        const unsigned long long mk = __ballot(mv);
        if (lane == 0) {
            bmg[b * 626 + 2 * g]     = (unsigned int)mk;
            bmg[b * 626 + 2 * g + 1] = (unsigned int)(mk >> 32);
        }
        any |= (mk != 0ull) ? 1 : 0;
    }
    if (any) atomicOr(&s_any, 1);
    __syncthreads();
    if (s_any && tid < Kk) pmask[(size_t)b * Kk + tid] = 1.f;
}

// ---------------------------------------------------------------------------
// Fused mid: blocks 0..1249 = compute_S (proven R15/R16 v4);
//            blocks 1250..1505 = compact (proven R16 v5, NSEG=128)
// ---------------------------------------------------------------------------
__global__ __launch_bounds__(256) void k_mid(
    const float* __restrict__ x, const int* __restrict__ mask,
    const unsigned short* __restrict__ Wf,
    const float* __restrict__ b1, const float* __restrict__ b2,
    unsigned int* __restrict__ Sh,
    const int* __restrict__ ei, const float* __restrict__ ew,
    const unsigned int* __restrict__ bmg,
    int* __restrict__ uvp, float* __restrict__ eww, int* __restrict__ cnt)
{
    __shared__ float b1s[Kk];
    __shared__ float b2s[Kk];
    __shared__ unsigned int bm[626];

    const int tid  = threadIdx.x;
    const int lane = tid & 63;
    const int wid  = tid >> 6;

    if (blockIdx.x < CS_BLOCKS) {
        // ----- compute_S branch -----
        if (tid < Kk) { b1s[tid] = b1[tid]; b2s[tid] = b2[tid]; }
        __syncthreads();

        const int hsel = lane >> 5;
        const int m32  = lane & 31;

        const int wc = blockIdx.x * WAVES_PER_BLOCK + wid;
        const int chunksPerBatch = Nn / 32;
        const int b  = wc / chunksPerBatch;
        const int n0 = (wc % chunksPerBatch) * 32;
        const int nd = n0 + m32;

        const unsigned short* W1A = Wf;
        const unsigned short* W2A = Wf + 8192;

        const float* xrow = x + ((size_t)b * Nn + nd) * Cc;
        f32x16 accA = 0.f, accB = 0.f;
        #pragma unroll
        for (int cs = 0; cs < 8; ++cs) {
            const float4 f0 = *(const float4*)&xrow[cs * 16 + hsel * 8];
            const float4 f1 = *(const float4*)&xrow[cs * 16 + hsel * 8 + 4];
            bf16x8 xa;
            xa[0] = (short)f2bf(f0.x); xa[1] = (short)f2bf(f0.y);
            xa[2] = (short)f2bf(f0.z); xa[3] = (short)f2bf(f0.w);
            xa[4] = (short)f2bf(f1.x); xa[5] = (short)f2bf(f1.y);
            xa[6] = (short)f2bf(f1.z); xa[7] = (short)f2bf(f1.w);
            const bf16x8 w1h0 = *(const bf16x8*)&W1A[((cs * 2 + 0) * 64 + lane) * 8];
            const bf16x8 w1h1 = *(const bf16x8*)&W1A[((cs * 2 + 1) * 64 + lane) * 8];
            accA = __builtin_amdgcn_mfma_f32_32x32x16_bf16(w1h0, xa, accA, 0, 0, 0);
            accB = __builtin_amdgcn_mfma_f32_32x32x16_bf16(w1h1, xa, accB, 0, 0, 0);
        }

        f32x16 accS0 = 0.f, accS1 = 0.f;

#define EXTRACT_GEMM2(KS, ACC)                                                 \
        {                                                                      \
            bf16x8 hf;                                                         \
            _Pragma("unroll")                                                  \
            for (int jj = 0; jj < 4; ++jj) {                                   \
                const int c0 = jj + 8 * ((KS) & 1);                            \
                const float own  = hsel ? (ACC)[c0 + 4] : (ACC)[c0];           \
                const float send = hsel ? (ACC)[c0]     : (ACC)[c0 + 4];       \
                const float sw   = __shfl_xor(send, 32);                       \
                const float vlo  = hsel ? sw  : own;                           \
                const float vhi  = hsel ? own : sw;                            \
                const int klo = (KS) * 16 + 8 * hsel + jj;                     \
                hf[jj]     = (short)f2bf(fmaxf(vlo + b1s[klo], 0.f));          \
                hf[jj + 4] = (short)f2bf(fmaxf(vhi + b1s[klo + 4], 0.f));      \
            }                                                                  \
            const bf16x8 w2l0 = *(const bf16x8*)&W2A[(((KS) * 2 + 0) * 64 + lane) * 8]; \
            const bf16x8 w2l1 = *(const bf16x8*)&W2A[(((KS) * 2 + 1) * 64 + lane) * 8]; \
            accS0 = __builtin_amdgcn_mfma_f32_32x32x16_bf16(w2l0, hf, accS0, 0, 0, 0); \
            accS1 = __builtin_amdgcn_mfma_f32_32x32x16_bf16(w2l1, hf, accS1, 0, 0, 0); \
        }

        EXTRACT_GEMM2(0, accA)
        EXTRACT_GEMM2(1, accA)
        EXTRACT_GEMM2(2, accB)
        EXTRACT_GEMM2(3, accB)
#undef EXTRACT_GEMM2

        float z0[16], z1[16];
        float mm = -1e30f;
        #pragma unroll
        for (int r = 0; r < 16; ++r) {
            const int l = (r & 3) + 8 * (r >> 2) + 4 * hsel;
            z0[r] = accS0[r] + b2s[l];
            z1[r] = accS1[r] + b2s[l + 32];
            mm = fmaxf(mm, fmaxf(z0[r], z1[r]));
        }
        mm = fmaxf(mm, __shfl_xor(mm, 32));
        float ssum = 0.f;
        #pragma unroll
        for (int r = 0; r < 16; ++r) {
            z0[r] = __expf(z0[r] - mm);
            z1[r] = __expf(z1[r] - mm);
            ssum += z0[r] + z1[r];
        }
        ssum += __shfl_xor(ssum, 32);
        const int   mv = mask[(size_t)b * Nn + nd];
        const float rs = (mv > 0) ? (1.f / ssum) : 0.f;

        unsigned int* ShRow = Sh + ((size_t)b * Nn + nd) * 32;
        #pragma unroll
        for (int g = 0; g < 4; ++g) {
            uint4 pk;
            pk.x = (unsigned int)f2bf(z0[4*g+0]*rs) | ((unsigned int)f2bf(z1[4*g+0]*rs) << 16);
            pk.y = (unsigned int)f2bf(z0[4*g+1]*rs) | ((unsigned int)f2bf(z1[4*g+1]*rs) << 16);
            pk.z = (unsigned int)f2bf(z0[4*g+2]*rs) | ((unsigned int)f2bf(z1[4*g+2]*rs) << 16);
            pk.w = (unsigned int)f2bf(z0[4*g+3]*rs) | ((unsigned int)f2bf(z1[4*g+3]*rs) << 16);
            *(uint4*)&ShRow[8 * g + 4 * hsel] = pk;
        }
        return;
    }

    // ----- compact branch (proven R16 v5, NSEG=128) -----
    const int cbid = blockIdx.x - CS_BLOCKS;        // 0..255
    const int b    = cbid & 7;
    const int seg  = (cbid >> 3) * 4 + wid;         // 0..NSEG-1
    const int groupsPerBatch = Ee / 64;             // 5000
    const size_t eib = (size_t)b * 2 * Ee;
    const float* ewb = ew + (size_t)b * Ee;
    int*   uvs  = uvp + ((size_t)b * NSEG + seg) * SEGCAP;
    float* ewws = eww + ((size_t)b * NSEG + seg) * SEGCAP;

    for (int i = tid; i < 626; i += 256) bm[i] = bmg[b * 626 + i];
    __syncthreads();

    int run = 0;
    for (int g = seg; g < groupsPerBatch; g += 8 * NSEG) {
        int u8[8], v8[8]; float w8[8]; int has[8];
        #pragma unroll
        for (int t = 0; t < 8; ++t) {
            const int gg = g + t * NSEG;
            has[t] = (gg < groupsPerBatch);
            const int e0 = (has[t] ? gg : g) * 64;
            u8[t] = ei[eib + e0 + lane];
            v8[t] = ei[eib + Ee + e0 + lane];
            w8[t] = ewb[e0 + lane];
        }
        #pragma unroll
        for (int t = 0; t < 8; ++t) {
            if (!has[t]) continue;                  // wave-uniform
            const unsigned int uu = (unsigned int)u8[t];
            const unsigned int vv = (unsigned int)v8[t];
            const bool valid = ((bm[uu >> 5] >> (uu & 31)) & 1u) &&
                               ((bm[vv >> 5] >> (vv & 31)) & 1u);
            const unsigned long long mk = __ballot(valid);
            const int myoff = __popcll(mk & ((1ull << lane) - 1ull));
            if (valid) {
                uvs[run + myoff]  = u8[t] | (v8[t] << 15);
                ewws[run + myoff] = w8[t];
            }
            run += (int)__popcll(mk);
        }
    }
    const int ncp = (run + 31) & ~31;
    if (lane < ncp - run) { uvs[run + lane] = 0; ewws[run + lane] = 0.f; }
    if (lane == 0) cnt[b * NSEG + seg] = ncp;
}

// ---------------------------------------------------------------------------
// Fused big: blocks 0..255 = pooled (proven R12/R16 2-deep pipeline, NSEG=128)
//            blocks 256..767 = pfeat (proven R10-R16)
// ---------------------------------------------------------------------------
template<bool USE_PT>
__global__ __launch_bounds__(256, 1) void k_big(
    const unsigned int* __restrict__ Sh, const int* __restrict__ uvp,
    const float* __restrict__ eww, const int* __restrict__ cnt,
    float* __restrict__ out,                        // pt or pooled
    const float* __restrict__ x, float* __restrict__ pfeat)
{
    __shared__ float tile[Kk * Kk];                 // 16 KB (pooled branch)
    const int tid  = threadIdx.x;
    const int lane = tid & 63;
    const int wid  = tid >> 6;
    const int hsel = lane >> 5;
    const int m32  = lane & 31;

    if (blockIdx.x < PL_BLOCKS) {
        // ----- pooled branch -----
        for (int i = tid; i < Kk * Kk; i += 256) tile[i] = 0.f;
        __syncthreads();

        const int b   = blockIdx.x & 7;             // XCD-pinned batch
        const int seg = (blockIdx.x >> 3) * 4 + wid;
        const unsigned int* Shb = Sh + (size_t)b * Nn * 32;
        const int*   uvs  = uvp + ((size_t)b * NSEG + seg) * SEGCAP;
        const float* ewws = eww + ((size_t)b * NSEG + seg) * SEGCAP;
        const int nc = cnt[b * NSEG + seg];         // multiple of 32

        f32x16 acc00 = 0.f, acc01 = 0.f, acc10 = 0.f, acc11 = 0.f;

#define LOADUV(UV, WW, BASE)                                        \
        _Pragma("unroll")                                           \
        for (int j = 0; j < 8; ++j) {                               \
            int sidx = (BASE) + hsel * 8 + j;                       \
            sidx = (sidx < nc) ? sidx : (nc - 1);                   \
            (UV)[j] = uvs[sidx];                                    \
            (WW)[j] = ewws[sidx];                                   \
        }

#define GATHER(GV, GU, UV)                                          \
        _Pragma("unroll")                                           \
        for (int j = 0; j < 8; ++j) {                               \
            const int uu = (UV)[j] & 32767;                         \
            const int vv = ((UV)[j] >> 15) & 32767;                 \
            (GV)[j] = Shb[(size_t)vv * 32 + m32];                   \
            (GU)[j] = Shb[(size_t)uu * 32 + m32];                   \
        }

#define CONSUME(GV, GU, WW)                                         \
        {                                                           \
            bf16x8 a0, a1, b0, b1;                                  \
            _Pragma("unroll")                                       \
            for (int j = 0; j < 8; ++j) {                           \
                a0[j] = (short)f2bf((WW)[j] * bf2f((GV)[j] & 0xffffu)); \
                a1[j] = (short)f2bf((WW)[j] * bf2f((GV)[j] >> 16)); \
                b0[j] = (short)((GU)[j] & 0xffffu);                 \
                b1[j] = (short)((GU)[j] >> 16);                     \
            }                                                       \
            acc00 = __builtin_amdgcn_mfma_f32_32x32x16_bf16(a0, b0, acc00, 0, 0, 0); \
            acc01 = __builtin_amdgcn_mfma_f32_32x32x16_bf16(a0, b1, acc01, 0, 0, 0); \
            acc10 = __builtin_amdgcn_mfma_f32_32x32x16_bf16(a1, b0, acc10, 0, 0, 0); \
            acc11 = __builtin_amdgcn_mfma_f32_32x32x16_bf16(a1, b1, acc11, 0, 0, 0); \
        }

        if (nc > 0) {
            int uvA[8], uvB[8];
            float wwA[8], wwB[8];
            unsigned int gvA[8], guA[8], gvB[8], guB[8];

            LOADUV(uvA, wwA, 0)
            GATHER(gvA, guA, uvA)
            LOADUV(uvB, wwB, 16)

            for (int c0 = 0; c0 < nc; c0 += 32) {
                GATHER(gvB, guB, uvB)
                int uvA2[8], uvB2[8]; float wwA2[8], wwB2[8];
                LOADUV(uvA2, wwA2, c0 + 32)
                LOADUV(uvB2, wwB2, c0 + 48)
                CONSUME(gvA, guA, wwA)
                GATHER(gvA, guA, uvA2)
                CONSUME(gvB, guB, wwB)
                #pragma unroll
                for (int j = 0; j < 8; ++j) {
                    uvB[j] = uvB2[j]; wwB[j] = wwB2[j]; wwA[j] = wwA2[j];
                }
            }
        }
#undef LOADUV
#undef GATHER
#undef CONSUME

        const int rbase = 4 * (lane >> 5);
        const int col   = lane & 31;
        #pragma unroll
        for (int r = 0; r < 16; ++r) {
            const int row = (r & 3) + 8 * (r >> 2) + rbase;
            atomicAdd(&tile[row * Kk + col],              acc00[r]);
            atomicAdd(&tile[row * Kk + 32 + col],         acc01[r]);
            atomicAdd(&tile[(32 + row) * Kk + col],       acc10[r]);
            atomicAdd(&tile[(32 + row) * Kk + 32 + col],  acc11[r]);
        }
        __syncthreads();

        if (USE_PT) {
            float* pt = out + (size_t)blockIdx.x * (Kk * Kk);
            for (int i = tid; i < Kk * Kk; i += 256) pt[i] = tile[i];
        } else {
            float* pb = out + (size_t)b * Kk * Kk;
            for (int i = tid; i < Kk * Kk; i += 256) atomicAdd(&pb[i], tile[i]);
        }
        return;
    }

    // ----- pfeat branch -----
    const int pbid = blockIdx.x - PL_BLOCKS;        // 0..511
    const int b    = pbid & 7;
    const int slot = pbid >> 3;
    const int bpb  = PF_BLOCKS >> 3;                // 64

    const float* xb = x + (size_t)b * Nn * Cc;
    const unsigned int* Shb = Sh + (size_t)b * Nn * 32;

    const int nodeoff = (lane >> 5) * 8;
    const int kc      = lane & 31;
    const int c       = wid * 32 + kc;

    f32x16 acc0 = 0.f, acc1 = 0.f;

    const int chunks = Nn / 16;
    for (int ch = slot; ch < chunks; ch += bpb) {
        const int nb = ch * 16 + nodeoff;
        unsigned int g[8]; float bff[8];
        #pragma unroll
        for (int j = 0; j < 8; ++j) {
            const size_t n = (size_t)(nb + j);
            g[j]   = Shb[n * 32 + kc];
            bff[j] = xb[n * Cc + c];
        }
        bf16x8 a0, a1, bbf;
        #pragma unroll
        for (int j = 0; j < 8; ++j) {
            a0[j]  = (short)(g[j] & 0xffffu);
            a1[j]  = (short)(g[j] >> 16);
            bbf[j] = (short)f2bf(bff[j]);
        }
        acc0 = __builtin_amdgcn_mfma_f32_32x32x16_bf16(a0, bbf, acc0, 0, 0, 0);
        acc1 = __builtin_amdgcn_mfma_f32_32x32x16_bf16(a1, bbf, acc1, 0, 0, 0);
    }

    float* pf = pfeat + (size_t)b * Kk * Cc;
    const int colc  = wid * 32 + (lane & 31);
    const int rbase = 4 * (lane >> 5);
    #pragma unroll
    for (int r = 0; r < 16; ++r) {
        const int row = (r & 3) + 8 * (r >> 2) + rbase;
        atomicAdd(&pf[row * Cc + colc],        acc0[r]);
        atomicAdd(&pf[(32 + row) * Cc + colc], acc1[r]);
    }
}

// ---------------------------------------------------------------------------
// Reduce: sum 32 partial tiles per batch; coalesced, 64 blocks.
// ---------------------------------------------------------------------------
__global__ __launch_bounds__(256) void k_reduce_pooled(
    const float* __restrict__ pt, float* __restrict__ pooled)
{
    const int b    = blockIdx.x & 7;
    const int part = blockIdx.x >> 3;               // 0..7
    const int tid  = threadIdx.x;
    #pragma unroll
    for (int i2 = 0; i2 < 2; ++i2) {
        const int i = part * 512 + i2 * 256 + tid;
        float s = 0.f;
        #pragma unroll 8
        for (int slot = 0; slot < 32; ++slot)
            s += pt[(size_t)(slot * 8 + b) * (Kk * Kk) + i];
        pooled[(size_t)b * Kk * Kk + i] = s;
    }
}

// ---------------------------------------------------------------------------
extern "C" void kernel_launch(void* const* d_in, const int* in_sizes, int n_in,
                              void* d_out, int out_size, void* d_ws, size_t ws_size,
                              hipStream_t stream)
{
    const float* x    = (const float*)d_in[0];
    const int*   ei   = (const int*)d_in[1];     // int64 ref -> int32 on device
    const float* ew   = (const float*)d_in[2];
    const int*   mask = (const int*)d_in[3];
    const float* W1   = (const float*)d_in[4];
    const float* b1   = (const float*)d_in[5];
    const float* W2   = (const float*)d_in[6];
    const float* b2   = (const float*)d_in[7];

    float* out    = (float*)d_out;
    float* pfeat  = out;
    float* pooled = out + (size_t)Bb * Kk * Cc;
    float* pmask  = out + (size_t)Bb * Kk * Cc + (size_t)Bb * Kk * Kk;

    // workspace layout (essentials first, pt last)
    unsigned int* Sh = (unsigned int*)d_ws;                     // 20.48 MB
    int*   uvp  = (int*)(Sh + (size_t)Bb * Nn * 32);            // 10.49 MB
    float* eww  = (float*)(uvp + (size_t)Bb * NSEG * SEGCAP);   // 10.49 MB
    int*   cnt  = (int*)(eww + (size_t)Bb * NSEG * SEGCAP);     // 4 KB
    unsigned int* bmg = (unsigned int*)(cnt + Bb * NSEG);       // 20 KB
    unsigned short* Wf = (unsigned short*)(bmg + Bb * 626);     // 24.5 KB
    float* pt   = (float*)(Wf + 12288);                         // 4.19 MB
    const size_t needed = (size_t)((char*)(pt + (size_t)PL_BLOCKS * Kk * Kk) - (char*)d_ws);
    const bool use_pt = ws_size >= needed;

    hipMemsetAsync(d_out, 0, sizeof(float) * (size_t)out_size, stream);

    k_init<<<65, 256, 0, stream>>>(W1, W2, mask, Wf, bmg, pmask);
    k_mid<<<CS_BLOCKS + CP_BLOCKS, 256, 0, stream>>>(
        x, mask, Wf, b1, b2, Sh, ei, ew, bmg, uvp, eww, cnt);
    if (use_pt) {
        k_big<true><<<PL_BLOCKS + PF_BLOCKS, 256, 0, stream>>>(
            Sh, uvp, eww, cnt, pt, x, pfeat);
        k_reduce_pooled<<<64, 256, 0, stream>>>(pt, pooled);
    } else {
        k_big<false><<<PL_BLOCKS + PF_BLOCKS, 256, 0, stream>>>(
            Sh, uvp, eww, cnt, pooled, x, pfeat);
    }
}

// Round 19
// 105.141 us; speedup vs baseline: 1.4350x; 1.0164x over previous
//
#include <hip/hip_runtime.h>

#define Bb 8
#define Nn 20000
#define Cc 128
#define Kk 64
#define Ee 320000

#define WAVES_PER_BLOCK 4
#define NSEG 128        // segments per batch (pooled: 256 blocks * 4 waves / 8 batches)
#define SEGCAP 2592     // 40 groups * 64 edges = 2560 max valid, padded to x48

#define CS_BLOCKS 1250
#define CP_BLOCKS 256
#define PL_BLOCKS 256
#define PF_BLOCKS 512

typedef __attribute__((ext_vector_type(8))) short bf16x8;
typedef __attribute__((ext_vector_type(16))) float f32x16;

__device__ __forceinline__ unsigned short f2bf(float f) {
    unsigned int u = __float_as_uint(f);
    u += 0x7FFFu + ((u >> 16) & 1u);          // round-to-nearest-even
    return (unsigned short)(u >> 16);
}
__device__ __forceinline__ float bf2f(unsigned int bits16) {
    return __uint_as_float(bits16 << 16);
}

// ---------------------------------------------------------------------------
// Fused init: block 0 = W-fragment prep; blocks 1..64 = mask bitmaps + pmask
// ---------------------------------------------------------------------------
__global__ __launch_bounds__(256) void k_init(
    const float* __restrict__ W1, const float* __restrict__ W2,
    const int* __restrict__ mask,
    unsigned short* __restrict__ Wf, unsigned int* __restrict__ bmg,
    float* __restrict__ pmask)
{
    __shared__ int s_any;
    const int tid = threadIdx.x;

    if (blockIdx.x == 0) {
        for (int idx = tid; idx < 8192; idx += 256) {
            const int j  = idx & 7;
            const int ln = (idx >> 3) & 63;
            const int t  = idx >> 9;
            const int kh = t & 1;
            const int cs = t >> 1;
            Wf[idx] = f2bf(W1[(cs * 16 + (ln >> 5) * 8 + j) * Kk + kh * 32 + (ln & 31)]);
        }
        for (int idx = tid; idx < 4096; idx += 256) {
            const int j  = idx & 7;
            const int ln = (idx >> 3) & 63;
            const int t  = idx >> 9;
            const int lh = t & 1;
            const int ks = t >> 1;
            Wf[8192 + idx] = f2bf(W2[(ks * 16 + (ln >> 5) * 8 + j) * Kk + lh * 32 + (ln & 31)]);
        }
        return;
    }

    const int bid  = blockIdx.x - 1;                // 0..63
    const int lane = tid & 63;
    const int wid  = tid >> 6;
    const int b    = bid & 7;
    const int part = bid >> 3;                      // 0..7
    if (tid == 0) s_any = 0;
    __syncthreads();

    const int* mb = mask + (size_t)b * Nn;
    int any = 0;
    for (int g = part * 4 + wid; g < 313; g += 32) {    // 313*64 >= 20000
        const int i = g * 64 + lane;
        const bool mv = (i < Nn) ? (mb[i] > 0) : false;
        const unsigned long long mk = __ballot(mv);
        if (lane == 0) {
            bmg[b * 626 + 2 * g]     = (unsigned int)mk;
            bmg[b * 626 + 2 * g + 1] = (unsigned int)(mk >> 32);
        }
        any |= (mk != 0ull) ? 1 : 0;
    }
    if (any) atomicOr(&s_any, 1);
    __syncthreads();
    if (s_any && tid < Kk) pmask[(size_t)b * Kk + tid] = 1.f;
}

// ---------------------------------------------------------------------------
// Fused mid: blocks 0..1249 = compute_S (proven R15-R18);
//            blocks 1250..1505 = compact (proven R16-R18, NSEG=128, pad x48)
// ---------------------------------------------------------------------------
__global__ __launch_bounds__(256) void k_mid(
    const float* __restrict__ x, const int* __restrict__ mask,
    const unsigned short* __restrict__ Wf,
    const float* __restrict__ b1, const float* __restrict__ b2,
    unsigned int* __restrict__ Sh,
    const int* __restrict__ ei, const float* __restrict__ ew,
    const unsigned int* __restrict__ bmg,
    int* __restrict__ uvp, float* __restrict__ eww, int* __restrict__ cnt)
{
    __shared__ float b1s[Kk];
    __shared__ float b2s[Kk];
    __shared__ unsigned int bm[626];

    const int tid  = threadIdx.x;
    const int lane = tid & 63;
    const int wid  = tid >> 6;

    if (blockIdx.x < CS_BLOCKS) {
        // ----- compute_S branch -----
        if (tid < Kk) { b1s[tid] = b1[tid]; b2s[tid] = b2[tid]; }
        __syncthreads();

        const int hsel = lane >> 5;
        const int m32  = lane & 31;

        const int wc = blockIdx.x * WAVES_PER_BLOCK + wid;
        const int chunksPerBatch = Nn / 32;
        const int b  = wc / chunksPerBatch;
        const int n0 = (wc % chunksPerBatch) * 32;
        const int nd = n0 + m32;

        const unsigned short* W1A = Wf;
        const unsigned short* W2A = Wf + 8192;

        const float* xrow = x + ((size_t)b * Nn + nd) * Cc;
        f32x16 accA = 0.f, accB = 0.f;
        #pragma unroll
        for (int cs = 0; cs < 8; ++cs) {
            const float4 f0 = *(const float4*)&xrow[cs * 16 + hsel * 8];
            const float4 f1 = *(const float4*)&xrow[cs * 16 + hsel * 8 + 4];
            bf16x8 xa;
            xa[0] = (short)f2bf(f0.x); xa[1] = (short)f2bf(f0.y);
            xa[2] = (short)f2bf(f0.z); xa[3] = (short)f2bf(f0.w);
            xa[4] = (short)f2bf(f1.x); xa[5] = (short)f2bf(f1.y);
            xa[6] = (short)f2bf(f1.z); xa[7] = (short)f2bf(f1.w);
            const bf16x8 w1h0 = *(const bf16x8*)&W1A[((cs * 2 + 0) * 64 + lane) * 8];
            const bf16x8 w1h1 = *(const bf16x8*)&W1A[((cs * 2 + 1) * 64 + lane) * 8];
            accA = __builtin_amdgcn_mfma_f32_32x32x16_bf16(w1h0, xa, accA, 0, 0, 0);
            accB = __builtin_amdgcn_mfma_f32_32x32x16_bf16(w1h1, xa, accB, 0, 0, 0);
        }

        f32x16 accS0 = 0.f, accS1 = 0.f;

#define EXTRACT_GEMM2(KS, ACC)                                                 \
        {                                                                      \
            bf16x8 hf;                                                         \
            _Pragma("unroll")                                                  \
            for (int jj = 0; jj < 4; ++jj) {                                   \
                const int c0 = jj + 8 * ((KS) & 1);                            \
                const float own  = hsel ? (ACC)[c0 + 4] : (ACC)[c0];           \
                const float send = hsel ? (ACC)[c0]     : (ACC)[c0 + 4];       \
                const float sw   = __shfl_xor(send, 32);                       \
                const float vlo  = hsel ? sw  : own;                           \
                const float vhi  = hsel ? own : sw;                            \
                const int klo = (KS) * 16 + 8 * hsel + jj;                     \
                hf[jj]     = (short)f2bf(fmaxf(vlo + b1s[klo], 0.f));          \
                hf[jj + 4] = (short)f2bf(fmaxf(vhi + b1s[klo + 4], 0.f));      \
            }                                                                  \
            const bf16x8 w2l0 = *(const bf16x8*)&W2A[(((KS) * 2 + 0) * 64 + lane) * 8]; \
            const bf16x8 w2l1 = *(const bf16x8*)&W2A[(((KS) * 2 + 1) * 64 + lane) * 8]; \
            accS0 = __builtin_amdgcn_mfma_f32_32x32x16_bf16(w2l0, hf, accS0, 0, 0, 0); \
            accS1 = __builtin_amdgcn_mfma_f32_32x32x16_bf16(w2l1, hf, accS1, 0, 0, 0); \
        }

        EXTRACT_GEMM2(0, accA)
        EXTRACT_GEMM2(1, accA)
        EXTRACT_GEMM2(2, accB)
        EXTRACT_GEMM2(3, accB)
#undef EXTRACT_GEMM2

        float z0[16], z1[16];
        float mm = -1e30f;
        #pragma unroll
        for (int r = 0; r < 16; ++r) {
            const int l = (r & 3) + 8 * (r >> 2) + 4 * hsel;
            z0[r] = accS0[r] + b2s[l];
            z1[r] = accS1[r] + b2s[l + 32];
            mm = fmaxf(mm, fmaxf(z0[r], z1[r]));
        }
        mm = fmaxf(mm, __shfl_xor(mm, 32));
        float ssum = 0.f;
        #pragma unroll
        for (int r = 0; r < 16; ++r) {
            z0[r] = __expf(z0[r] - mm);
            z1[r] = __expf(z1[r] - mm);
            ssum += z0[r] + z1[r];
        }
        ssum += __shfl_xor(ssum, 32);
        const int   mv = mask[(size_t)b * Nn + nd];
        const float rs = (mv > 0) ? (1.f / ssum) : 0.f;

        unsigned int* ShRow = Sh + ((size_t)b * Nn + nd) * 32;
        #pragma unroll
        for (int g = 0; g < 4; ++g) {
            uint4 pk;
            pk.x = (unsigned int)f2bf(z0[4*g+0]*rs) | ((unsigned int)f2bf(z1[4*g+0]*rs) << 16);
            pk.y = (unsigned int)f2bf(z0[4*g+1]*rs) | ((unsigned int)f2bf(z1[4*g+1]*rs) << 16);
            pk.z = (unsigned int)f2bf(z0[4*g+2]*rs) | ((unsigned int)f2bf(z1[4*g+2]*rs) << 16);
            pk.w = (unsigned int)f2bf(z0[4*g+3]*rs) | ((unsigned int)f2bf(z1[4*g+3]*rs) << 16);
            *(uint4*)&ShRow[8 * g + 4 * hsel] = pk;
        }
        return;
    }

    // ----- compact branch (pads to x48 for pooled's unroll-3 pipeline) -----
    const int cbid = blockIdx.x - CS_BLOCKS;        // 0..255
    const int b    = cbid & 7;
    const int seg  = (cbid >> 3) * 4 + wid;         // 0..NSEG-1
    const int groupsPerBatch = Ee / 64;             // 5000
    const size_t eib = (size_t)b * 2 * Ee;
    const float* ewb = ew + (size_t)b * Ee;
    int*   uvs  = uvp + ((size_t)b * NSEG + seg) * SEGCAP;
    float* ewws = eww + ((size_t)b * NSEG + seg) * SEGCAP;

    for (int i = tid; i < 626; i += 256) bm[i] = bmg[b * 626 + i];
    __syncthreads();

    int run = 0;
    for (int g = seg; g < groupsPerBatch; g += 8 * NSEG) {
        int u8[8], v8[8]; float w8[8]; int has[8];
        #pragma unroll
        for (int t = 0; t < 8; ++t) {
            const int gg = g + t * NSEG;
            has[t] = (gg < groupsPerBatch);
            const int e0 = (has[t] ? gg : g) * 64;
            u8[t] = ei[eib + e0 + lane];
            v8[t] = ei[eib + Ee + e0 + lane];
            w8[t] = ewb[e0 + lane];
        }
        #pragma unroll
        for (int t = 0; t < 8; ++t) {
            if (!has[t]) continue;                  // wave-uniform
            const unsigned int uu = (unsigned int)u8[t];
            const unsigned int vv = (unsigned int)v8[t];
            const bool valid = ((bm[uu >> 5] >> (uu & 31)) & 1u) &&
                               ((bm[vv >> 5] >> (vv & 31)) & 1u);
            const unsigned long long mk = __ballot(valid);
            const int myoff = __popcll(mk & ((1ull << lane) - 1ull));
            if (valid) {
                uvs[run + myoff]  = u8[t] | (v8[t] << 15);
                ewws[run + myoff] = w8[t];
            }
            run += (int)__popcll(mk);
        }
    }
    const int ncp = ((run + 47) / 48) * 48;         // pad to x48
    if (lane < ncp - run) { uvs[run + lane] = 0; ewws[run + lane] = 0.f; }
    if (lane == 0) cnt[b * NSEG + seg] = ncp;
}

// ---------------------------------------------------------------------------
// Fused big: blocks 0..255 = pooled (3-chunk-deep gather pipeline, step 16,
//            unroll-3, atomic flush); blocks 256..767 = pfeat (proven).
// ---------------------------------------------------------------------------
__global__ __launch_bounds__(256, 1) void k_big(
    const unsigned int* __restrict__ Sh, const int* __restrict__ uvp,
    const float* __restrict__ eww, const int* __restrict__ cnt,
    float* __restrict__ pooled,
    const float* __restrict__ x, float* __restrict__ pfeat)
{
    __shared__ float tile[Kk * Kk];                 // 16 KB (pooled branch)
    const int tid  = threadIdx.x;
    const int lane = tid & 63;
    const int wid  = tid >> 6;
    const int hsel = lane >> 5;
    const int m32  = lane & 31;

    if (blockIdx.x < PL_BLOCKS) {
        // ----- pooled branch -----
        for (int i = tid; i < Kk * Kk; i += 256) tile[i] = 0.f;
        __syncthreads();

        const int b   = blockIdx.x & 7;             // XCD-pinned batch
        const int seg = (blockIdx.x >> 3) * 4 + wid;
        const unsigned int* Shb = Sh + (size_t)b * Nn * 32;
        const int*   uvs  = uvp + ((size_t)b * NSEG + seg) * SEGCAP;
        const float* ewws = eww + ((size_t)b * NSEG + seg) * SEGCAP;
        const int nc = cnt[b * NSEG + seg];         // multiple of 48

        f32x16 acc00 = 0.f, acc01 = 0.f, acc10 = 0.f, acc11 = 0.f;

#define LOADUV(UV, WW, BASE)                                        \
        _Pragma("unroll")                                           \
        for (int j = 0; j < 8; ++j) {                               \
            int sidx = (BASE) + hsel * 8 + j;                       \
            sidx = (sidx < nc) ? sidx : (nc - 1);                   \
            (UV)[j] = uvs[sidx];                                    \
            (WW)[j] = ewws[sidx];                                   \
        }

#define GATHER(GV, GU, UV)                                          \
        _Pragma("unroll")                                           \
        for (int j = 0; j < 8; ++j) {                               \
            const int uu = (UV)[j] & 32767;                         \
            const int vv = ((UV)[j] >> 15) & 32767;                 \
            (GV)[j] = Shb[(size_t)vv * 32 + m32];                   \
            (GU)[j] = Shb[(size_t)uu * 32 + m32];                   \
        }

#define CONSUME(GV, GU, WW)                                         \
        {                                                           \
            bf16x8 a0, a1, b0, b1;                                  \
            _Pragma("unroll")                                       \
            for (int j = 0; j < 8; ++j) {                           \
                a0[j] = (short)f2bf((WW)[j] * bf2f((GV)[j] & 0xffffu)); \
                a1[j] = (short)f2bf((WW)[j] * bf2f((GV)[j] >> 16)); \
                b0[j] = (short)((GU)[j] & 0xffffu);                 \
                b1[j] = (short)((GU)[j] >> 16);                     \
            }                                                       \
            acc00 = __builtin_amdgcn_mfma_f32_32x32x16_bf16(a0, b0, acc00, 0, 0, 0); \
            acc01 = __builtin_amdgcn_mfma_f32_32x32x16_bf16(a0, b1, acc01, 0, 0, 0); \
            acc10 = __builtin_amdgcn_mfma_f32_32x32x16_bf16(a1, b0, acc10, 0, 0, 0); \
            acc11 = __builtin_amdgcn_mfma_f32_32x32x16_bf16(a1, b1, acc11, 0, 0, 0); \
        }

        if (nc > 0) {
            // chunk step = 16 edges; 3 uv sets + 3 gather sets live
            int uvA[8], uvB[8], uvC[8];
            float wwA[8], wwB[8], wwC[8];
            unsigned int gvA[8], guA[8], gvB[8], guB[8], gvC[8], guC[8];

            LOADUV(uvA, wwA, 0)
            LOADUV(uvB, wwB, 16)
            LOADUV(uvC, wwC, 32)
            GATHER(gvA, guA, uvA)       // chunk 0 in flight
            GATHER(gvB, guB, uvB)       // chunk 1 in flight

            for (int c0 = 0; c0 < nc; c0 += 48) {
                int uvD[8], uvE[8], uvF[8];
                float wwD[8], wwE[8], wwF[8];
                // sub 1: consume chunk c0
                LOADUV(uvD, wwD, c0 + 48)
                GATHER(gvC, guC, uvC)            // chunk c0+32
                CONSUME(gvA, guA, wwA)
                // sub 2: consume chunk c0+16
                LOADUV(uvE, wwE, c0 + 64)
                GATHER(gvA, guA, uvD)            // chunk c0+48 (next iter's A)
                CONSUME(gvB, guB, wwB)
                // sub 3: consume chunk c0+32
                LOADUV(uvF, wwF, c0 + 80)
                GATHER(gvB, guB, uvE)            // chunk c0+64 (next iter's B)
                CONSUME(gvC, guC, wwC)
                // rotate ww/uv state for next iteration
                #pragma unroll
                for (int j = 0; j < 8; ++j) {
                    wwA[j] = wwD[j]; wwB[j] = wwE[j]; wwC[j] = wwF[j];
                    uvC[j] = uvF[j];
                }
            }
        }
#undef LOADUV
#undef GATHER
#undef CONSUME

        const int rbase = 4 * (lane >> 5);
        const int col   = lane & 31;
        #pragma unroll
        for (int r = 0; r < 16; ++r) {
            const int row = (r & 3) + 8 * (r >> 2) + rbase;
            atomicAdd(&tile[row * Kk + col],              acc00[r]);
            atomicAdd(&tile[row * Kk + 32 + col],         acc01[r]);
            atomicAdd(&tile[(32 + row) * Kk + col],       acc10[r]);
            atomicAdd(&tile[(32 + row) * Kk + 32 + col],  acc11[r]);
        }
        __syncthreads();

        float* pb = pooled + (size_t)b * Kk * Kk;
        for (int i = tid; i < Kk * Kk; i += 256)
            atomicAdd(&pb[i], tile[i]);
        return;
    }

    // ----- pfeat branch (proven R10-R18) -----
    const int pbid = blockIdx.x - PL_BLOCKS;        // 0..511
    const int b    = pbid & 7;
    const int slot = pbid >> 3;
    const int bpb  = PF_BLOCKS >> 3;                // 64

    const float* xb = x + (size_t)b * Nn * Cc;
    const unsigned int* Shb = Sh + (size_t)b * Nn * 32;

    const int nodeoff = (lane >> 5) * 8;
    const int kc      = lane & 31;
    const int c       = wid * 32 + kc;

    f32x16 acc0 = 0.f, acc1 = 0.f;

    const int chunks = Nn / 16;
    for (int ch = slot; ch < chunks; ch += bpb) {
        const int nb = ch * 16 + nodeoff;
        unsigned int g[8]; float bff[8];
        #pragma unroll
        for (int j = 0; j < 8; ++j) {
            const size_t n = (size_t)(nb + j);
            g[j]   = Shb[n * 32 + kc];
            bff[j] = xb[n * Cc + c];
        }
        bf16x8 a0, a1, bbf;
        #pragma unroll
        for (int j = 0; j < 8; ++j) {
            a0[j]  = (short)(g[j] & 0xffffu);
            a1[j]  = (short)(g[j] >> 16);
            bbf[j] = (short)f2bf(bff[j]);
        }
        acc0 = __builtin_amdgcn_mfma_f32_32x32x16_bf16(a0, bbf, acc0, 0, 0, 0);
        acc1 = __builtin_amdgcn_mfma_f32_32x32x16_bf16(a1, bbf, acc1, 0, 0, 0);
    }

    float* pf = pfeat + (size_t)b * Kk * Cc;
    const int colc  = wid * 32 + (lane & 31);
    const int rbase = 4 * (lane >> 5);
    #pragma unroll
    for (int r = 0; r < 16; ++r) {
        const int row = (r & 3) + 8 * (r >> 2) + rbase;
        atomicAdd(&pf[row * Cc + colc],        acc0[r]);
        atomicAdd(&pf[(32 + row) * Cc + colc], acc1[r]);
    }
}

// ---------------------------------------------------------------------------
extern "C" void kernel_launch(void* const* d_in, const int* in_sizes, int n_in,
                              void* d_out, int out_size, void* d_ws, size_t ws_size,
                              hipStream_t stream)
{
    const float* x    = (const float*)d_in[0];
    const int*   ei   = (const int*)d_in[1];     // int64 ref -> int32 on device
    const float* ew   = (const float*)d_in[2];
    const int*   mask = (const int*)d_in[3];
    const float* W1   = (const float*)d_in[4];
    const float* b1   = (const float*)d_in[5];
    const float* W2   = (const float*)d_in[6];
    const float* b2   = (const float*)d_in[7];

    float* out    = (float*)d_out;
    float* pfeat  = out;
    float* pooled = out + (size_t)Bb * Kk * Cc;
    float* pmask  = out + (size_t)Bb * Kk * Cc + (size_t)Bb * Kk * Kk;

    // workspace layout
    unsigned int* Sh = (unsigned int*)d_ws;                     // 20.48 MB
    int*   uvp  = (int*)(Sh + (size_t)Bb * Nn * 32);            // 10.62 MB
    float* eww  = (float*)(uvp + (size_t)Bb * NSEG * SEGCAP);   // 10.62 MB
    int*   cnt  = (int*)(eww + (size_t)Bb * NSEG * SEGCAP);     // 4 KB
    unsigned int* bmg = (unsigned int*)(cnt + Bb * NSEG);       // 20 KB
    unsigned short* Wf = (unsigned short*)(bmg + Bb * 626);     // 24.5 KB

    hipMemsetAsync(d_out, 0, sizeof(float) * (size_t)out_size, stream);

    k_init<<<65, 256, 0, stream>>>(W1, W2, mask, Wf, bmg, pmask);
    k_mid<<<CS_BLOCKS + CP_BLOCKS, 256, 0, stream>>>(
        x, mask, Wf, b1, b2, Sh, ei, ew, bmg, uvp, eww, cnt);
    k_big<<<PL_BLOCKS + PF_BLOCKS, 256, 0, stream>>>(
        Sh, uvp, eww, cnt, pooled, x, pfeat);
}

// Round 20
// 101.476 us; speedup vs baseline: 1.4868x; 1.0361x over previous
//
#include <hip/hip_runtime.h>

#define Bb 8
#define Nn 20000
#define Cc 128
#define Kk 64
#define Ee 320000

#define WAVES_PER_BLOCK 4
#define NSEG 128        // segments per batch (pooled: 256 blocks * 4 waves / 8 batches)
#define SEGCAP 2560     // 40 groups * 64 edges, padded to x32

#define CS_BLOCKS 1250
#define CP_BLOCKS 256
#define PL_BLOCKS 256
#define PF_BLOCKS 512

typedef __attribute__((ext_vector_type(8))) short bf16x8;
typedef __attribute__((ext_vector_type(16))) float f32x16;

__device__ __forceinline__ unsigned short f2bf(float f) {
    unsigned int u = __float_as_uint(f);
    u += 0x7FFFu + ((u >> 16) & 1u);          // round-to-nearest-even
    return (unsigned short)(u >> 16);
}
__device__ __forceinline__ float bf2f(unsigned int bits16) {
    return __uint_as_float(bits16 << 16);
}

// ---------------------------------------------------------------------------
// Fused init: block 0 = W-fragment prep; blocks 1..64 = mask bitmaps + pmask
// ---------------------------------------------------------------------------
__global__ __launch_bounds__(256) void k_init(
    const float* __restrict__ W1, const float* __restrict__ W2,
    const int* __restrict__ mask,
    unsigned short* __restrict__ Wf, unsigned int* __restrict__ bmg,
    float* __restrict__ pmask)
{
    __shared__ int s_any;
    const int tid = threadIdx.x;

    if (blockIdx.x == 0) {
        for (int idx = tid; idx < 8192; idx += 256) {
            const int j  = idx & 7;
            const int ln = (idx >> 3) & 63;
            const int t  = idx >> 9;
            const int kh = t & 1;
            const int cs = t >> 1;
            Wf[idx] = f2bf(W1[(cs * 16 + (ln >> 5) * 8 + j) * Kk + kh * 32 + (ln & 31)]);
        }
        for (int idx = tid; idx < 4096; idx += 256) {
            const int j  = idx & 7;
            const int ln = (idx >> 3) & 63;
            const int t  = idx >> 9;
            const int lh = t & 1;
            const int ks = t >> 1;
            Wf[8192 + idx] = f2bf(W2[(ks * 16 + (ln >> 5) * 8 + j) * Kk + lh * 32 + (ln & 31)]);
        }
        return;
    }

    const int bid  = blockIdx.x - 1;                // 0..63
    const int lane = tid & 63;
    const int wid  = tid >> 6;
    const int b    = bid & 7;
    const int part = bid >> 3;                      // 0..7
    if (tid == 0) s_any = 0;
    __syncthreads();

    const int* mb = mask + (size_t)b * Nn;
    int any = 0;
    for (int g = part * 4 + wid; g < 313; g += 32) {    // 313*64 >= 20000
        const int i = g * 64 + lane;
        const bool mv = (i < Nn) ? (mb[i] > 0) : false;
        const unsigned long long mk = __ballot(mv);
        if (lane == 0) {
            bmg[b * 626 + 2 * g]     = (unsigned int)mk;
            bmg[b * 626 + 2 * g + 1] = (unsigned int)(mk >> 32);
        }
        any |= (mk != 0ull) ? 1 : 0;
    }
    if (any) atomicOr(&s_any, 1);
    __syncthreads();
    if (s_any && tid < Kk) pmask[(size_t)b * Kk + tid] = 1.f;
}

// ---------------------------------------------------------------------------
// Fused mid: blocks 0..1249 = compute_S (proven R15-R19);
//            blocks 1250..1505 = compact (proven R16-R19, NSEG=128, pad x32)
// ---------------------------------------------------------------------------
__global__ __launch_bounds__(256) void k_mid(
    const float* __restrict__ x, const int* __restrict__ mask,
    const unsigned short* __restrict__ Wf,
    const float* __restrict__ b1, const float* __restrict__ b2,
    unsigned int* __restrict__ Sh,
    const int* __restrict__ ei, const float* __restrict__ ew,
    const unsigned int* __restrict__ bmg,
    int* __restrict__ uvp, float* __restrict__ eww, int* __restrict__ cnt)
{
    __shared__ float b1s[Kk];
    __shared__ float b2s[Kk];
    __shared__ unsigned int bm[626];

    const int tid  = threadIdx.x;
    const int lane = tid & 63;
    const int wid  = tid >> 6;

    if (blockIdx.x < CS_BLOCKS) {
        // ----- compute_S branch -----
        if (tid < Kk) { b1s[tid] = b1[tid]; b2s[tid] = b2[tid]; }
        __syncthreads();

        const int hsel = lane >> 5;
        const int m32  = lane & 31;

        const int wc = blockIdx.x * WAVES_PER_BLOCK + wid;
        const int chunksPerBatch = Nn / 32;
        const int b  = wc / chunksPerBatch;
        const int n0 = (wc % chunksPerBatch) * 32;
        const int nd = n0 + m32;

        const unsigned short* W1A = Wf;
        const unsigned short* W2A = Wf + 8192;

        const float* xrow = x + ((size_t)b * Nn + nd) * Cc;
        f32x16 accA = 0.f, accB = 0.f;
        #pragma unroll
        for (int cs = 0; cs < 8; ++cs) {
            const float4 f0 = *(const float4*)&xrow[cs * 16 + hsel * 8];
            const float4 f1 = *(const float4*)&xrow[cs * 16 + hsel * 8 + 4];
            bf16x8 xa;
            xa[0] = (short)f2bf(f0.x); xa[1] = (short)f2bf(f0.y);
            xa[2] = (short)f2bf(f0.z); xa[3] = (short)f2bf(f0.w);
            xa[4] = (short)f2bf(f1.x); xa[5] = (short)f2bf(f1.y);
            xa[6] = (short)f2bf(f1.z); xa[7] = (short)f2bf(f1.w);
            const bf16x8 w1h0 = *(const bf16x8*)&W1A[((cs * 2 + 0) * 64 + lane) * 8];
            const bf16x8 w1h1 = *(const bf16x8*)&W1A[((cs * 2 + 1) * 64 + lane) * 8];
            accA = __builtin_amdgcn_mfma_f32_32x32x16_bf16(w1h0, xa, accA, 0, 0, 0);
            accB = __builtin_amdgcn_mfma_f32_32x32x16_bf16(w1h1, xa, accB, 0, 0, 0);
        }

        f32x16 accS0 = 0.f, accS1 = 0.f;

#define EXTRACT_GEMM2(KS, ACC)                                                 \
        {                                                                      \
            bf16x8 hf;                                                         \
            _Pragma("unroll")                                                  \
            for (int jj = 0; jj < 4; ++jj) {                                   \
                const int c0 = jj + 8 * ((KS) & 1);                            \
                const float own  = hsel ? (ACC)[c0 + 4] : (ACC)[c0];           \
                const float send = hsel ? (ACC)[c0]     : (ACC)[c0 + 4];       \
                const float sw   = __shfl_xor(send, 32);                       \
                const float vlo  = hsel ? sw  : own;                           \
                const float vhi  = hsel ? own : sw;                            \
                const int klo = (KS) * 16 + 8 * hsel + jj;                     \
                hf[jj]     = (short)f2bf(fmaxf(vlo + b1s[klo], 0.f));          \
                hf[jj + 4] = (short)f2bf(fmaxf(vhi + b1s[klo + 4], 0.f));      \
            }                                                                  \
            const bf16x8 w2l0 = *(const bf16x8*)&W2A[(((KS) * 2 + 0) * 64 + lane) * 8]; \
            const bf16x8 w2l1 = *(const bf16x8*)&W2A[(((KS) * 2 + 1) * 64 + lane) * 8]; \
            accS0 = __builtin_amdgcn_mfma_f32_32x32x16_bf16(w2l0, hf, accS0, 0, 0, 0); \
            accS1 = __builtin_amdgcn_mfma_f32_32x32x16_bf16(w2l1, hf, accS1, 0, 0, 0); \
        }

        EXTRACT_GEMM2(0, accA)
        EXTRACT_GEMM2(1, accA)
        EXTRACT_GEMM2(2, accB)
        EXTRACT_GEMM2(3, accB)
#undef EXTRACT_GEMM2

        float z0[16], z1[16];
        float mm = -1e30f;
        #pragma unroll
        for (int r = 0; r < 16; ++r) {
            const int l = (r & 3) + 8 * (r >> 2) + 4 * hsel;
            z0[r] = accS0[r] + b2s[l];
            z1[r] = accS1[r] + b2s[l + 32];
            mm = fmaxf(mm, fmaxf(z0[r], z1[r]));
        }
        mm = fmaxf(mm, __shfl_xor(mm, 32));
        float ssum = 0.f;
        #pragma unroll
        for (int r = 0; r < 16; ++r) {
            z0[r] = __expf(z0[r] - mm);
            z1[r] = __expf(z1[r] - mm);
            ssum += z0[r] + z1[r];
        }
        ssum += __shfl_xor(ssum, 32);
        const int   mv = mask[(size_t)b * Nn + nd];
        const float rs = (mv > 0) ? (1.f / ssum) : 0.f;

        unsigned int* ShRow = Sh + ((size_t)b * Nn + nd) * 32;
        #pragma unroll
        for (int g = 0; g < 4; ++g) {
            uint4 pk;
            pk.x = (unsigned int)f2bf(z0[4*g+0]*rs) | ((unsigned int)f2bf(z1[4*g+0]*rs) << 16);
            pk.y = (unsigned int)f2bf(z0[4*g+1]*rs) | ((unsigned int)f2bf(z1[4*g+1]*rs) << 16);
            pk.z = (unsigned int)f2bf(z0[4*g+2]*rs) | ((unsigned int)f2bf(z1[4*g+2]*rs) << 16);
            pk.w = (unsigned int)f2bf(z0[4*g+3]*rs) | ((unsigned int)f2bf(z1[4*g+3]*rs) << 16);
            *(uint4*)&ShRow[8 * g + 4 * hsel] = pk;
        }
        return;
    }

    // ----- compact branch (proven R16, pad x32) -----
    const int cbid = blockIdx.x - CS_BLOCKS;        // 0..255
    const int b    = cbid & 7;
    const int seg  = (cbid >> 3) * 4 + wid;         // 0..NSEG-1
    const int groupsPerBatch = Ee / 64;             // 5000
    const size_t eib = (size_t)b * 2 * Ee;
    const float* ewb = ew + (size_t)b * Ee;
    int*   uvs  = uvp + ((size_t)b * NSEG + seg) * SEGCAP;
    float* ewws = eww + ((size_t)b * NSEG + seg) * SEGCAP;

    for (int i = tid; i < 626; i += 256) bm[i] = bmg[b * 626 + i];
    __syncthreads();

    int run = 0;
    for (int g = seg; g < groupsPerBatch; g += 8 * NSEG) {
        int u8[8], v8[8]; float w8[8]; int has[8];
        #pragma unroll
        for (int t = 0; t < 8; ++t) {
            const int gg = g + t * NSEG;
            has[t] = (gg < groupsPerBatch);
            const int e0 = (has[t] ? gg : g) * 64;
            u8[t] = ei[eib + e0 + lane];
            v8[t] = ei[eib + Ee + e0 + lane];
            w8[t] = ewb[e0 + lane];
        }
        #pragma unroll
        for (int t = 0; t < 8; ++t) {
            if (!has[t]) continue;                  // wave-uniform
            const unsigned int uu = (unsigned int)u8[t];
            const unsigned int vv = (unsigned int)v8[t];
            const bool valid = ((bm[uu >> 5] >> (uu & 31)) & 1u) &&
                               ((bm[vv >> 5] >> (vv & 31)) & 1u);
            const unsigned long long mk = __ballot(valid);
            const int myoff = __popcll(mk & ((1ull << lane) - 1ull));
            if (valid) {
                uvs[run + myoff]  = u8[t] | (v8[t] << 15);
                ewws[run + myoff] = w8[t];
            }
            run += (int)__popcll(mk);
        }
    }
    const int ncp = (run + 31) & ~31;               // pad to x32
    if (lane < ncp - run) { uvs[run + lane] = 0; ewws[run + lane] = 0.f; }
    if (lane == 0) cnt[b * NSEG + seg] = ncp;
}

// ---------------------------------------------------------------------------
// Fused big: blocks 0..255 = pooled (R18-proven 2-deep pipeline, step 32,
//            atomic flush); blocks 256..767 = pfeat (proven).
// ---------------------------------------------------------------------------
__global__ __launch_bounds__(256, 1) void k_big(
    const unsigned int* __restrict__ Sh, const int* __restrict__ uvp,
    const float* __restrict__ eww, const int* __restrict__ cnt,
    float* __restrict__ pooled,
    const float* __restrict__ x, float* __restrict__ pfeat)
{
    __shared__ float tile[Kk * Kk];                 // 16 KB (pooled branch)
    const int tid  = threadIdx.x;
    const int lane = tid & 63;
    const int wid  = tid >> 6;
    const int hsel = lane >> 5;
    const int m32  = lane & 31;

    if (blockIdx.x < PL_BLOCKS) {
        // ----- pooled branch (exact R18 2-deep pipeline) -----
        for (int i = tid; i < Kk * Kk; i += 256) tile[i] = 0.f;
        __syncthreads();

        const int b   = blockIdx.x & 7;             // XCD-pinned batch
        const int seg = (blockIdx.x >> 3) * 4 + wid;
        const unsigned int* Shb = Sh + (size_t)b * Nn * 32;
        const int*   uvs  = uvp + ((size_t)b * NSEG + seg) * SEGCAP;
        const float* ewws = eww + ((size_t)b * NSEG + seg) * SEGCAP;
        const int nc = cnt[b * NSEG + seg];         // multiple of 32

        f32x16 acc00 = 0.f, acc01 = 0.f, acc10 = 0.f, acc11 = 0.f;

#define LOADUV(UV, WW, BASE)                                        \
        _Pragma("unroll")                                           \
        for (int j = 0; j < 8; ++j) {                               \
            int sidx = (BASE) + hsel * 8 + j;                       \
            sidx = (sidx < nc) ? sidx : (nc - 1);                   \
            (UV)[j] = uvs[sidx];                                    \
            (WW)[j] = ewws[sidx];                                   \
        }

#define GATHER(GV, GU, UV)                                          \
        _Pragma("unroll")                                           \
        for (int j = 0; j < 8; ++j) {                               \
            const int uu = (UV)[j] & 32767;                         \
            const int vv = ((UV)[j] >> 15) & 32767;                 \
            (GV)[j] = Shb[(size_t)vv * 32 + m32];                   \
            (GU)[j] = Shb[(size_t)uu * 32 + m32];                   \
        }

#define CONSUME(GV, GU, WW)                                         \
        {                                                           \
            bf16x8 a0, a1, b0, b1;                                  \
            _Pragma("unroll")                                       \
            for (int j = 0; j < 8; ++j) {                           \
                a0[j] = (short)f2bf((WW)[j] * bf2f((GV)[j] & 0xffffu)); \
                a1[j] = (short)f2bf((WW)[j] * bf2f((GV)[j] >> 16)); \
                b0[j] = (short)((GU)[j] & 0xffffu);                 \
                b1[j] = (short)((GU)[j] >> 16);                     \
            }                                                       \
            acc00 = __builtin_amdgcn_mfma_f32_32x32x16_bf16(a0, b0, acc00, 0, 0, 0); \
            acc01 = __builtin_amdgcn_mfma_f32_32x32x16_bf16(a0, b1, acc01, 0, 0, 0); \
            acc10 = __builtin_amdgcn_mfma_f32_32x32x16_bf16(a1, b0, acc10, 0, 0, 0); \
            acc11 = __builtin_amdgcn_mfma_f32_32x32x16_bf16(a1, b1, acc11, 0, 0, 0); \
        }

        if (nc > 0) {
            int uvA[8], uvB[8];
            float wwA[8], wwB[8];
            unsigned int gvA[8], guA[8], gvB[8], guB[8];

            LOADUV(uvA, wwA, 0)
            GATHER(gvA, guA, uvA)
            LOADUV(uvB, wwB, 16)

            for (int c0 = 0; c0 < nc; c0 += 32) {
                GATHER(gvB, guB, uvB)
                int uvA2[8], uvB2[8]; float wwA2[8], wwB2[8];
                LOADUV(uvA2, wwA2, c0 + 32)
                LOADUV(uvB2, wwB2, c0 + 48)
                CONSUME(gvA, guA, wwA)
                GATHER(gvA, guA, uvA2)
                CONSUME(gvB, guB, wwB)
                #pragma unroll
                for (int j = 0; j < 8; ++j) {
                    uvB[j] = uvB2[j]; wwB[j] = wwB2[j]; wwA[j] = wwA2[j];
                }
            }
        }
#undef LOADUV
#undef GATHER
#undef CONSUME

        const int rbase = 4 * (lane >> 5);
        const int col   = lane & 31;
        #pragma unroll
        for (int r = 0; r < 16; ++r) {
            const int row = (r & 3) + 8 * (r >> 2) + rbase;
            atomicAdd(&tile[row * Kk + col],              acc00[r]);
            atomicAdd(&tile[row * Kk + 32 + col],         acc01[r]);
            atomicAdd(&tile[(32 + row) * Kk + col],       acc10[r]);
            atomicAdd(&tile[(32 + row) * Kk + 32 + col],  acc11[r]);
        }
        __syncthreads();

        float* pb = pooled + (size_t)b * Kk * Kk;
        for (int i = tid; i < Kk * Kk; i += 256)
            atomicAdd(&pb[i], tile[i]);
        return;
    }

    // ----- pfeat branch (proven R10-R19) -----
    const int pbid = blockIdx.x - PL_BLOCKS;        // 0..511
    const int b    = pbid & 7;
    const int slot = pbid >> 3;
    const int bpb  = PF_BLOCKS >> 3;                // 64

    const float* xb = x + (size_t)b * Nn * Cc;
    const unsigned int* Shb = Sh + (size_t)b * Nn * 32;

    const int nodeoff = (lane >> 5) * 8;
    const int kc      = lane & 31;
    const int c       = wid * 32 + kc;

    f32x16 acc0 = 0.f, acc1 = 0.f;

    const int chunks = Nn / 16;
    for (int ch = slot; ch < chunks; ch += bpb) {
        const int nb = ch * 16 + nodeoff;
        unsigned int g[8]; float bff[8];
        #pragma unroll
        for (int j = 0; j < 8; ++j) {
            const size_t n = (size_t)(nb + j);
            g[j]   = Shb[n * 32 + kc];
            bff[j] = xb[n * Cc + c];
        }
        bf16x8 a0, a1, bbf;
        #pragma unroll
        for (int j = 0; j < 8; ++j) {
            a0[j]  = (short)(g[j] & 0xffffu);
            a1[j]  = (short)(g[j] >> 16);
            bbf[j] = (short)f2bf(bff[j]);
        }
        acc0 = __builtin_amdgcn_mfma_f32_32x32x16_bf16(a0, bbf, acc0, 0, 0, 0);
        acc1 = __builtin_amdgcn_mfma_f32_32x32x16_bf16(a1, bbf, acc1, 0, 0, 0);
    }

    float* pf = pfeat + (size_t)b * Kk * Cc;
    const int colc  = wid * 32 + (lane & 31);
    const int rbase = 4 * (lane >> 5);
    #pragma unroll
    for (int r = 0; r < 16; ++r) {
        const int row = (r & 3) + 8 * (r >> 2) + rbase;
        atomicAdd(&pf[row * Cc + colc],        acc0[r]);
        atomicAdd(&pf[(32 + row) * Cc + colc], acc1[r]);
    }
}

// ---------------------------------------------------------------------------
extern "C" void kernel_launch(void* const* d_in, const int* in_sizes, int n_in,
                              void* d_out, int out_size, void* d_ws, size_t ws_size,
                              hipStream_t stream)
{
    const float* x    = (const float*)d_in[0];
    const int*   ei   = (const int*)d_in[1];     // int64 ref -> int32 on device
    const float* ew   = (const float*)d_in[2];
    const int*   mask = (const int*)d_in[3];
    const float* W1   = (const float*)d_in[4];
    const float* b1   = (const float*)d_in[5];
    const float* W2   = (const float*)d_in[6];
    const float* b2   = (const float*)d_in[7];

    float* out    = (float*)d_out;
    float* pfeat  = out;
    float* pooled = out + (size_t)Bb * Kk * Cc;
    float* pmask  = out + (size_t)Bb * Kk * Cc + (size_t)Bb * Kk * Kk;

    // workspace layout
    unsigned int* Sh = (unsigned int*)d_ws;                     // 20.48 MB
    int*   uvp  = (int*)(Sh + (size_t)Bb * Nn * 32);            // 10.49 MB
    float* eww  = (float*)(uvp + (size_t)Bb * NSEG * SEGCAP);   // 10.49 MB
    int*   cnt  = (int*)(eww + (size_t)Bb * NSEG * SEGCAP);     // 4 KB
    unsigned int* bmg = (unsigned int*)(cnt + Bb * NSEG);       // 20 KB
    unsigned short* Wf = (unsigned short*)(bmg + Bb * 626);     // 24.5 KB

    hipMemsetAsync(d_out, 0, sizeof(float) * (size_t)out_size, stream);

    k_init<<<65, 256, 0, stream>>>(W1, W2, mask, Wf, bmg, pmask);
    k_mid<<<CS_BLOCKS + CP_BLOCKS, 256, 0, stream>>>(
        x, mask, Wf, b1, b2, Sh, ei, ew, bmg, uvp, eww, cnt);
    k_big<<<PL_BLOCKS + PF_BLOCKS, 256, 0, stream>>>(
        Sh, uvp, eww, cnt, pooled, x, pfeat);
}